// Round 19
// baseline (186.803 us; speedup 1.0000x reference)
//
#include <hip/hip_runtime.h>
#include <stdint.h>

#define B_ 4
#define S_ 2048
#define D_ 1024
#define H_ 16
#define A_ 64
#define M_ (B_*S_)    // 8192
#define BH_ (B_*H_)   // 64
#define INV_LN2 1.4426950408889634f

typedef _Float16 f16x8 __attribute__((ext_vector_type(8)));
typedef float    f32x4 __attribute__((ext_vector_type(4)));

__device__ __forceinline__ uint32_t f2h(float f) {
    _Float16 h = (_Float16)f;                      // RNE
    return (uint32_t)__builtin_bit_cast(uint16_t, h);
}

__device__ __forceinline__ float exp2f_fast(float x) {
    return __builtin_amdgcn_exp2f(x);              // v_exp_f32: computes 2^x
}

__device__ __forceinline__ uint32_t pkrtz(float a, float b) {
    return __builtin_bit_cast(uint32_t, __builtin_amdgcn_cvt_pkrtz(a, b));
}

// XOR swizzle for [R][64]-f16 LDS tiles (row stride 128 B)
__device__ __forceinline__ int swz(int row, int col) {
    return (row * 64 + col) ^ ((row & 7) << 3);
}

// ---------------------------------------------------------------- prep: W -> Wt[p][h][a][d] f16
// p==0 (Wq) additionally scaled by 1/ln2 so QK^T scores land in log2 domain.
__global__ __launch_bounds__(256) void prep_w(
    const float* __restrict__ Wq, const float* __restrict__ Wk, const float* __restrict__ Wv,
    uint16_t* __restrict__ Wt)
{
    __shared__ float tile[64][65];
    const int dt = blockIdx.x, h = blockIdx.y, p = blockIdx.z;
    const float* W = (p == 0) ? Wq : (p == 1) ? Wk : Wv;
    const float sc = (p == 0) ? INV_LN2 : 1.0f;
    const float* src = W + (h * D_ + dt * 64) * A_;   // [64 d][64 a]
    const int t = threadIdx.x;
    const int r0 = t >> 4, c4 = (t & 15) * 4;
    #pragma unroll
    for (int i = 0; i < 4; i++) {
        int r = r0 + i * 16;
        float4 x = *(const float4*)(src + r * A_ + c4);
        tile[r][c4] = x.x; tile[r][c4 + 1] = x.y; tile[r][c4 + 2] = x.z; tile[r][c4 + 3] = x.w;
    }
    __syncthreads();
    uint16_t* dst = Wt + (p * H_ + h) * (A_ * D_) + dt * 64;
    #pragma unroll
    for (int i = 0; i < 4; i++) {
        int a = r0 + i * 16;
        int d4 = (t & 15) * 4;
        uint2 o2;
        o2.x = f2h(tile[d4][a] * sc)     | (f2h(tile[d4 + 1][a] * sc) << 16);
        o2.y = f2h(tile[d4 + 2][a] * sc) | (f2h(tile[d4 + 3][a] * sc) << 16);
        *(uint2*)(dst + a * D_ + d4) = o2;
    }
}

// ---------------------------------------------------------------- projection GEMM
// Fused f32 input, BK=32, double-buffered 48 KB LDS.
// A: register-staged (8 f32 loads -> 4 pkrtz -> 16B ds_write); B: global_load_lds.
// ONE barrier per K-step; vmcnt(0) sits after compute.
// NOTE: no min-waves launch bound — forcing 6 waves/EU spilled accumulators (R16).
__global__ __launch_bounds__(512) void proj_kernel(
    const float* __restrict__ qsrc, const float* __restrict__ ksrc, const float* __restrict__ vsrc,
    const uint16_t* __restrict__ Wt,
    const float* __restrict__ bq, const float* __restrict__ bk, const float* __restrict__ bv,
    uint16_t* __restrict__ qh, uint16_t* __restrict__ kh, uint16_t* __restrict__ vpv)
{
    __shared__ __align__(16) uint16_t As[2][128 * 32];   // 2 x 8 KB
    __shared__ __align__(16) uint16_t Bs[2][256 * 32];   // 2 x 16 KB  rows: h'*64 + a
    const int p = blockIdx.z, nt = blockIdx.y, mt = blockIdx.x;
    const int t = threadIdx.x, lane = t & 63, w = t >> 6;
    const int wr = w >> 2, wc = w & 3;
    const int lr = lane & 15, lg = lane >> 4;
    const int Mbase = mt * 128;
    const float* Af = (p == 0) ? qsrc : (p == 1) ? ksrc : vsrc;

    // A reg staging: thread t -> row t>>2 (0..127), logical slot t&3 (8 f32 cols).
    const int ar  = t >> 2;
    const int als = t & 3;
    const int afx = (ar >> 1) & 3;                       // f(row)
    const float* asrc = Af + (size_t)(Mbase + ar) * D_ + als * 8;
    const int awoff = ar * 32 + ((als ^ afx) * 8);       // phys slot = logical ^ f(row)

    // B staging via global_load_lds: thread t -> row t>>2 (+128), phys slot t&3
    // sources logical slot (t&3) ^ f(row).
    const int bslot = (t & 3) ^ (((t >> 2) >> 1) & 3);
    const uint16_t* bsrc[2];
    #pragma unroll
    for (int i = 0; i < 2; i++) {
        int row = (t >> 2) + 128 * i;                    // 0..255: h' = row>>6, a = row&63
        bsrc[i] = Wt + ((size_t)(p * H_ + nt * 4 + (row >> 6)) * A_ + (row & 63)) * D_ + bslot * 8;
    }

    f32x4 acc[4][4] = {};

    #define BSTAGE(buf, kkv) do {                                                                  \
        __builtin_amdgcn_global_load_lds(bsrc[0] + (kkv), (char*)(&Bs[buf][0]) + w * 1024,        16, 0, 0); \
        __builtin_amdgcn_global_load_lds(bsrc[1] + (kkv), (char*)(&Bs[buf][0]) + 8192 + w * 1024, 16, 0, 0); \
    } while (0)

    #define AWRITE(buf, v0, v1) do {                                                               \
        uint4 u_;                                                                                  \
        u_.x = pkrtz((v0).x, (v0).y); u_.y = pkrtz((v0).z, (v0).w);                                \
        u_.z = pkrtz((v1).x, (v1).y); u_.w = pkrtz((v1).z, (v1).w);                                \
        *(uint4*)(&As[buf][awoff]) = u_;                                                           \
    } while (0)

    // prologue: stage tile 0
    {
        BSTAGE(0, 0);
        float4 a0 = *(const float4*)(asrc);
        float4 a1 = *(const float4*)(asrc + 4);
        asm volatile("s_waitcnt vmcnt(0)" ::: "memory");
        AWRITE(0, a0, a1);
        __syncthreads();
    }

    const int NKS = D_ / 32;   // 32
    for (int ks = 0; ks < NKS; ks++) {
        const int cur = ks & 1, nxt = cur ^ 1;
        const bool hasNext = (ks + 1 < NKS);
        float4 a0, a1;
        if (hasNext) {
            BSTAGE(nxt, (ks + 1) * 32);
            a0 = *(const float4*)(asrc + (ks + 1) * 32);
            a1 = *(const float4*)(asrc + (ks + 1) * 32 + 4);
        }

        // compute tile ks
        f16x8 af[4], bf[4];
        #pragma unroll
        for (int mb = 0; mb < 4; mb++) {
            const int r = wr * 64 + mb * 16 + lr;
            af[mb] = *(const f16x8*)(&As[cur][r * 32 + ((lg ^ ((r >> 1) & 3)) * 8)]);
        }
        #pragma unroll
        for (int nb = 0; nb < 4; nb++) {
            const int r = wc * 64 + nb * 16 + lr;
            bf[nb] = *(const f16x8*)(&Bs[cur][r * 32 + ((lg ^ ((r >> 1) & 3)) * 8)]);
        }
        #pragma unroll
        for (int mb = 0; mb < 4; mb++) {
            #pragma unroll
            for (int nb = 0; nb < 4; nb++)
                acc[mb][nb] = __builtin_amdgcn_mfma_f32_16x16x32_f16(af[mb], bf[nb], acc[mb][nb], 0, 0, 0);
        }

        if (hasNext) {
            asm volatile("s_waitcnt vmcnt(0)" ::: "memory");   // B(ks+1) in LDS; a0/a1 valid
            __builtin_amdgcn_sched_barrier(0);
            AWRITE(nxt, a0, a1);
            __syncthreads();   // closes reads of buf cur + makes A(ks+1) visible
        }
    }
    #undef BSTAGE
    #undef AWRITE

    const int h = nt * 4 + wc;
    const int b = Mbase >> 11;
    const int bh = b * H_ + h;
    const int sbase = Mbase & (S_ - 1);
    const float* bias = ((p == 0) ? bq : (p == 1) ? bk : bv) + h * A_;
    const float bsc = (p == 0) ? INV_LN2 : 1.0f;
    #pragma unroll
    for (int mb = 0; mb < 4; mb++) {
        #pragma unroll
        for (int nb = 0; nb < 4; nb++) {
            const int a = nb * 16 + lr;
            const float bia = bias[a] * bsc;
            const int s0 = sbase + wr * 64 + mb * 16 + 4 * lg;
            if (p < 2) {
                uint16_t* o = (p == 0) ? qh : kh;
                #pragma unroll
                for (int r = 0; r < 4; r++)
                    o[(bh * S_ + s0 + r) * A_ + a] = (uint16_t)f2h(acc[mb][nb][r] + bia);
            } else {
                const int kt2 = s0 >> 6, kv0 = s0 & 63;
                const int kb2 = kv0 >> 5, jhi = (kv0 >> 4) & 1, lg2 = (kv0 >> 2) & 3;
                uint2 pk2;
                pk2.x = f2h(acc[mb][nb][0] + bia) | (f2h(acc[mb][nb][1] + bia) << 16);
                pk2.y = f2h(acc[mb][nb][2] + bia) | (f2h(acc[mb][nb][3] + bia) << 16);
                *(uint2*)(vpv + ((size_t)((bh * 32 + kt2) * 512 + kb2 * 256 + lg2 * 64 + a)) * 8 + 4 * jhi) = pk2;
            }
        }
    }
}

// ---------------------------------------------------------------- flash attention
// 512 thr / 8 waves, QBLK=128, KVBLK=64. Asymmetric staging depth:
// K[3] (2-tile prefetch cover, consumed at tile start) + V[2] (1-tile issue
// distance; consumed at tile END -> effective ~1.4-tile cover) = 40 KB LDS
// -> exactly 4 blocks/CU, grid 1024 = 4/CU: ZERO residency tail.
// Issue order per tile: V(t+1) then K(t+2); in-flight before tile t's wait is
// [K(t), V(t), K(t+1)] -> vmcnt(1) guarantees K(t)+V(t) landed, keeps K(t+1)
// in flight. Barrier makes it collective. XCD remap, swapped QK^T with
// C-init = -m, per-lane defer-check, l-sum via ones-MFMA, pkrtz packing,
// full-line stores via LDS restage (32 KB, fits in the 40 KB).
__global__ __launch_bounds__(512, 8) void flash_kernel(
    const uint16_t* __restrict__ qh, const uint16_t* __restrict__ kh,
    const uint16_t* __restrict__ vpv, float* __restrict__ out)
{
    __shared__ __align__(16) uint16_t smem[20480];   // K[3]: 0..12287 | V[2]: 12288..20479 (u16)
    const int t = threadIdx.x, lane = t & 63, w = t >> 6;   // w: 0..7
    const int lr = lane & 15, lg = lane >> 4;

    // XCD-locality remap: 16 same-bh blocks land on one XCD's L2
    const int flat = blockIdx.y * gridDim.x + blockIdx.x;   // 0..1023
    const int nf = (flat & 7) * 128 + (flat >> 3);
    const int qt = nf & 15, bh = nf >> 4;
    const int b = bh >> 4, h = bh & (H_ - 1);

    // Q as B-fragment: lane (lr,lg) holds Q[q = qt*128 + w*16 + lr][d = kb*32+8*lg+j]
    f16x8 qf[2];
    {
        const uint16_t* qp = qh + (size_t)(bh * S_ + qt * 128 + w * 16 + lr) * A_ + 8 * lg;
        qf[0] = *(const f16x8*)(qp);
        qf[1] = *(const f16x8*)(qp + 32);
    }
    f16x8 ones;
    #pragma unroll
    for (int j = 0; j < 8; j++) ones[j] = (_Float16)1.0f;

    // Staging: 512 lanes x 16 B = one full 8 KB tile per instruction.
    const int row0 = t >> 3;           // 0..63
    const int col0 = (t * 8) & 63;
    const int scol = col0 ^ ((row0 & 7) << 3);
    const uint16_t* kg = kh + (size_t)(bh * S_ + row0) * A_ + scol;
    const uint16_t* vg = vpv + (size_t)bh * (S_ * A_) + t * 8;

    // negm = -m of q-row lr (log2 domain), all 4 comps equal; feeds QK C-init.
    f32x4 negm = {};
    f32x4 oacc[4] = {};
    f32x4 lsum = {};

    #define KSTAGE(buf, kt_) \
        __builtin_amdgcn_global_load_lds(kg + (size_t)(kt_) * (64 * A_), \
                                         smem + (buf) * 4096 + w * 512, 16, 0, 0)
    #define VSTAGE(buf, kt_) \
        __builtin_amdgcn_global_load_lds(vg + (size_t)(kt_) * 4096, \
                                         smem + 12288 + (buf) * 4096 + w * 512, 16, 0, 0)

    const int NT = S_ / 64;   // 32
    KSTAGE(0, 0); VSTAGE(0, 0); KSTAGE(1, 1);   // in-flight: [K0, V0, K1]

    int kcur = 0;   // kt % 3
    for (int kt = 0; kt < NT; kt++) {
        if (kt < NT - 1) asm volatile("s_waitcnt vmcnt(1)" ::: "memory");   // K(kt),V(kt) landed; K(kt+1) in flight
        else             asm volatile("s_waitcnt vmcnt(0)" ::: "memory");
        __builtin_amdgcn_s_barrier();       // all waves' tile kt visible
        __builtin_amdgcn_sched_barrier(0);
        if (kt + 1 < NT) VSTAGE((kt + 1) & 1, kt + 1);   // V-buf's readers (tile kt-1) closed above
        if (kt + 2 < NT) {
            int kb3 = kcur + 2; if (kb3 >= 3) kb3 -= 3;
            KSTAGE(kb3, kt + 2);                          // K-buf (kt-1)%3, closed above
        }
        __builtin_amdgcn_sched_barrier(0);
        const uint16_t* Kc = smem + kcur * 4096;
        const uint16_t* Vc = smem + 12288 + (kt & 1) * 4096;

        // QK^T swapped; C-init = negm: sacc[nb] = s(kv = nb*16+4*lg+r, q = lr) - m
        f32x4 sacc[4];
        __builtin_amdgcn_s_setprio(1);
        #pragma unroll
        for (int nb = 0; nb < 4; nb++) {
            f16x8 kf = *(const f16x8*)(Kc + swz(nb * 16 + lr, 8 * lg));
            sacc[nb] = __builtin_amdgcn_mfma_f32_16x16x32_f16(kf, qf[0], negm, 0, 0, 0);
        }
        #pragma unroll
        for (int nb = 0; nb < 4; nb++) {
            f16x8 kf = *(const f16x8*)(Kc + swz(nb * 16 + lr, 32 + 8 * lg));
            sacc[nb] = __builtin_amdgcn_mfma_f32_16x16x32_f16(kf, qf[1], sacc[nb], 0, 0, 0);
        }
        __builtin_amdgcn_s_setprio(0);

        // per-lane max over own 16 scores (no cross-lane reduce on the fast path)
        float a0 = fmaxf(fmaxf(sacc[0][0], sacc[0][1]), sacc[0][2]);
        float a1 = fmaxf(fmaxf(sacc[0][3], sacc[1][0]), sacc[1][1]);
        float a2 = fmaxf(fmaxf(sacc[1][2], sacc[1][3]), sacc[2][0]);
        float a3 = fmaxf(fmaxf(sacc[2][1], sacc[2][2]), sacc[2][3]);
        float a4 = fmaxf(fmaxf(sacc[3][0], sacc[3][1]), sacc[3][2]);
        float pm = fmaxf(fmaxf(fmaxf(a0, a1), fmaxf(a2, a3)), fmaxf(a4, sacc[3][3]));

        // defer-max: rescale only when some row grew past m+11 (P <= 2^11 < f16 max)
        if (__any(pm > 11.0f)) {
            float tm = fmaxf(pm, __shfl_xor(pm, 16));
            tm = fmaxf(tm, __shfl_xor(tm, 32));
            float delta = fmaxf(tm, 0.0f);
            float sc = exp2f_fast(-delta);
            #pragma unroll
            for (int r = 0; r < 4; r++) negm[r] -= delta;
            #pragma unroll
            for (int nb = 0; nb < 4; nb++) {
                #pragma unroll
                for (int r = 0; r < 4; r++) sacc[nb][r] -= delta;
            }
            float scr[4];
            #pragma unroll
            for (int r = 0; r < 4; r++) scr[r] = __shfl(sc, 4 * lg + r);
            #pragma unroll
            for (int r = 0; r < 4; r++) lsum[r] *= scr[r];
            #pragma unroll
            for (int nb = 0; nb < 4; nb++) {
                #pragma unroll
                for (int r = 0; r < 4; r++) oacc[nb][r] *= scr[r];
            }
        }

        // P = exp2(sacc) packed (pkrtz) directly into PV A-fragments
        f16x8 paf[2];
        #pragma unroll
        for (int kb2 = 0; kb2 < 2; kb2++) {
            float e[8];
            #pragma unroll
            for (int jh = 0; jh < 2; jh++) {
                #pragma unroll
                for (int r = 0; r < 4; r++)
                    e[jh * 4 + r] = exp2f_fast(sacc[2 * kb2 + jh][r]);
            }
            uint4 u;
            u.x = pkrtz(e[0], e[1]); u.y = pkrtz(e[2], e[3]);
            u.z = pkrtz(e[4], e[5]); u.w = pkrtz(e[6], e[7]);
            paf[kb2] = __builtin_bit_cast(f16x8, u);
        }

        // l-sum via ones-MFMA (row sums land in oacc row layout) + PV
        __builtin_amdgcn_s_setprio(1);
        lsum = __builtin_amdgcn_mfma_f32_16x16x32_f16(paf[0], ones, lsum, 0, 0, 0);
        lsum = __builtin_amdgcn_mfma_f32_16x16x32_f16(paf[1], ones, lsum, 0, 0, 0);
        #pragma unroll
        for (int kb2 = 0; kb2 < 2; kb2++) {
            #pragma unroll
            for (int nb = 0; nb < 4; nb++) {
                f16x8 vf = *(const f16x8*)(Vc + ((kb2 * 4 + lg) * 64 + nb * 16 + lr) * 8);
                oacc[nb] = __builtin_amdgcn_mfma_f32_16x16x32_f16(paf[kb2], vf, oacc[nb], 0, 0, 0);
            }
        }
        __builtin_amdgcn_s_setprio(0);

        kcur = (kcur == 2) ? 0 : kcur + 1;
    }
    #undef KSTAGE
    #undef VSTAGE

    // normalize into LDS (reusing K/V space), then full-line coalesced stores
    __syncthreads();   // all waves done with K/V LDS
    float* outs = (float*)smem;   // 128 x 64 f32 = 32 KB (fits in 40 KB)
    #pragma unroll
    for (int r = 0; r < 4; r++) {
        const float inv = 1.0f / lsum[r];
        const int sl = w * 16 + 4 * lg + r;
        #pragma unroll
        for (int nb = 0; nb < 4; nb++)
            outs[sl * 64 + nb * 16 + lr] = oacc[nb][r] * inv;
    }
    __syncthreads();
    const int orow = t >> 4, oslot = t & 15;
    float* obase = out + (size_t)(b * S_ + qt * 128 + orow) * (H_ * A_) + h * A_ + oslot * 4;
    #pragma unroll
    for (int i = 0; i < 4; i++)
        *(float4*)(obase + (size_t)(32 * i) * (H_ * A_)) =
            *(const float4*)(outs + (orow + 32 * i) * 64 + oslot * 4);
}

// ----------------------------------------------------------------
extern "C" void kernel_launch(void* const* d_in, const int* in_sizes, int n_in,
                              void* d_out, int out_size, void* d_ws, size_t ws_size,
                              hipStream_t stream)
{
    const float* q  = (const float*)d_in[0];
    const float* k  = (const float*)d_in[1];
    const float* v  = (const float*)d_in[2];
    const float* Wq = (const float*)d_in[3];
    const float* bq = (const float*)d_in[4];
    const float* Wk = (const float*)d_in[5];
    const float* bk = (const float*)d_in[6];
    const float* Wv = (const float*)d_in[7];
    const float* bv = (const float*)d_in[8];
    float* out = (float*)d_out;

    uint8_t* ws = (uint8_t*)d_ws;
    const size_t SZ_H  = (size_t)BH_ * S_ * A_ * 2;     // 16 MB each
    uint16_t* qh  = (uint16_t*)(ws);
    uint16_t* kh  = (uint16_t*)(ws + SZ_H);
    uint16_t* vpv = (uint16_t*)(ws + 2 * SZ_H);
    uint16_t* Wt  = (uint16_t*)(ws + 3 * SZ_H);

    prep_w<<<dim3(16, H_, 3), 256, 0, stream>>>(Wq, Wk, Wv, Wt);
    proj_kernel<<<dim3(M_ / 128, 4, 3), 512, 0, stream>>>(q, k, v, Wt,
                                                          bq, bk, bv, qh, kh, vpv);
    flash_kernel<<<dim3(S_ / 128, BH_), 512, 0, stream>>>(qh, kh, vpv, out);
}

// Round 20
// 166.184 us; speedup vs baseline: 1.1241x; 1.1241x over previous
//
#include <hip/hip_runtime.h>
#include <stdint.h>

#define B_ 4
#define S_ 2048
#define D_ 1024
#define H_ 16
#define A_ 64
#define M_ (B_*S_)    // 8192
#define BH_ (B_*H_)   // 64
#define INV_LN2 1.4426950408889634f

typedef _Float16 f16x8 __attribute__((ext_vector_type(8)));
typedef float    f32x4 __attribute__((ext_vector_type(4)));

__device__ __forceinline__ uint32_t f2h(float f) {
    _Float16 h = (_Float16)f;                      // RNE
    return (uint32_t)__builtin_bit_cast(uint16_t, h);
}

__device__ __forceinline__ float exp2f_fast(float x) {
    return __builtin_amdgcn_exp2f(x);              // v_exp_f32: computes 2^x
}

__device__ __forceinline__ uint32_t pkrtz(float a, float b) {
    return __builtin_bit_cast(uint32_t, __builtin_amdgcn_cvt_pkrtz(a, b));
}

// XOR swizzle for [R][64]-f16 LDS tiles (row stride 128 B)
__device__ __forceinline__ int swz(int row, int col) {
    return (row * 64 + col) ^ ((row & 7) << 3);
}

// ---------------------------------------------------------------- prep: W -> Wt[p][h][a][d] f16
// p==0 (Wq) additionally scaled by 1/ln2 so QK^T scores land in log2 domain.
__global__ __launch_bounds__(256) void prep_w(
    const float* __restrict__ Wq, const float* __restrict__ Wk, const float* __restrict__ Wv,
    uint16_t* __restrict__ Wt)
{
    __shared__ float tile[64][65];
    const int dt = blockIdx.x, h = blockIdx.y, p = blockIdx.z;
    const float* W = (p == 0) ? Wq : (p == 1) ? Wk : Wv;
    const float sc = (p == 0) ? INV_LN2 : 1.0f;
    const float* src = W + (h * D_ + dt * 64) * A_;   // [64 d][64 a]
    const int t = threadIdx.x;
    const int r0 = t >> 4, c4 = (t & 15) * 4;
    #pragma unroll
    for (int i = 0; i < 4; i++) {
        int r = r0 + i * 16;
        float4 x = *(const float4*)(src + r * A_ + c4);
        tile[r][c4] = x.x; tile[r][c4 + 1] = x.y; tile[r][c4 + 2] = x.z; tile[r][c4 + 3] = x.w;
    }
    __syncthreads();
    uint16_t* dst = Wt + (p * H_ + h) * (A_ * D_) + dt * 64;
    #pragma unroll
    for (int i = 0; i < 4; i++) {
        int a = r0 + i * 16;
        int d4 = (t & 15) * 4;
        uint2 o2;
        o2.x = f2h(tile[d4][a] * sc)     | (f2h(tile[d4 + 1][a] * sc) << 16);
        o2.y = f2h(tile[d4 + 2][a] * sc) | (f2h(tile[d4 + 3][a] * sc) << 16);
        *(uint2*)(dst + a * D_ + d4) = o2;
    }
}

// ---------------------------------------------------------------- projection GEMM
// Fused f32 input, BK=32, double-buffered 48 KB LDS, 2-STEP A prefetch:
// A(ks+2) issued at step ks; vmcnt(2) drains A(ks+1)+B(ks+1) only (issue order
// pinned B-then-A by sched_barrier); raw lgkmcnt(0)+s_barrier (NOT __syncthreads,
// whose vmcnt(0) would kill the in-flight cover). Loop unrolled x2 with named
// even/odd A-register pairs. NOTE: no min-waves bound (R16: forced 6/EU spilled).
__global__ __launch_bounds__(512) void proj_kernel(
    const float* __restrict__ qsrc, const float* __restrict__ ksrc, const float* __restrict__ vsrc,
    const uint16_t* __restrict__ Wt,
    const float* __restrict__ bq, const float* __restrict__ bk, const float* __restrict__ bv,
    uint16_t* __restrict__ qh, uint16_t* __restrict__ kh, uint16_t* __restrict__ vpv)
{
    __shared__ __align__(16) uint16_t As[2][128 * 32];   // 2 x 8 KB
    __shared__ __align__(16) uint16_t Bs[2][256 * 32];   // 2 x 16 KB  rows: h'*64 + a
    const int p = blockIdx.z, nt = blockIdx.y, mt = blockIdx.x;
    const int t = threadIdx.x, lane = t & 63, w = t >> 6;
    const int wr = w >> 2, wc = w & 3;
    const int lr = lane & 15, lg = lane >> 4;
    const int Mbase = mt * 128;
    const float* Af = (p == 0) ? qsrc : (p == 1) ? ksrc : vsrc;

    // A reg staging: thread t -> row t>>2 (0..127), logical slot t&3 (8 f32 cols).
    const int ar  = t >> 2;
    const int als = t & 3;
    const int afx = (ar >> 1) & 3;                       // f(row)
    const float* asrc = Af + (size_t)(Mbase + ar) * D_ + als * 8;
    const int awoff = ar * 32 + ((als ^ afx) * 8);       // phys slot = logical ^ f(row)

    // B staging via global_load_lds: thread t -> row t>>2 (+128), phys slot t&3
    // sources logical slot (t&3) ^ f(row).
    const int bslot = (t & 3) ^ (((t >> 2) >> 1) & 3);
    const uint16_t* bsrc0 = Wt + ((size_t)(p * H_ + nt * 4 + ((t >> 2) >> 6)) * A_ + ((t >> 2) & 63)) * D_ + bslot * 8;
    const uint16_t* bsrc1 = Wt + ((size_t)(p * H_ + nt * 4 + (((t >> 2) + 128) >> 6)) * A_ + ((t >> 2) & 63)) * D_ + bslot * 8;

    f32x4 acc[4][4] = {};

    #define BSTAGE(buf, kkv) do {                                                                  \
        __builtin_amdgcn_global_load_lds(bsrc0 + (kkv), (char*)(&Bs[buf][0]) + w * 1024,        16, 0, 0); \
        __builtin_amdgcn_global_load_lds(bsrc1 + (kkv), (char*)(&Bs[buf][0]) + 8192 + w * 1024, 16, 0, 0); \
    } while (0)

    #define AWRITE(buf, v0, v1) do {                                                               \
        uint4 u_;                                                                                  \
        u_.x = pkrtz((v0).x, (v0).y); u_.y = pkrtz((v0).z, (v0).w);                                \
        u_.z = pkrtz((v1).x, (v1).y); u_.w = pkrtz((v1).z, (v1).w);                                \
        *(uint4*)(&As[buf][awoff]) = u_;                                                           \
    } while (0)

    #define COMPUTE(buf) do {                                                                      \
        f16x8 af[4], bf[4];                                                                        \
        _Pragma("unroll")                                                                          \
        for (int mb = 0; mb < 4; mb++) {                                                           \
            const int r = wr * 64 + mb * 16 + lr;                                                  \
            af[mb] = *(const f16x8*)(&As[buf][r * 32 + ((lg ^ ((r >> 1) & 3)) * 8)]);              \
        }                                                                                          \
        _Pragma("unroll")                                                                          \
        for (int nb = 0; nb < 4; nb++) {                                                           \
            const int r = wc * 64 + nb * 16 + lr;                                                  \
            bf[nb] = *(const f16x8*)(&Bs[buf][r * 32 + ((lg ^ ((r >> 1) & 3)) * 8)]);              \
        }                                                                                          \
        _Pragma("unroll")                                                                          \
        for (int mb = 0; mb < 4; mb++) {                                                           \
            _Pragma("unroll")                                                                      \
            for (int nb = 0; nb < 4; nb++)                                                         \
                acc[mb][nb] = __builtin_amdgcn_mfma_f32_16x16x32_f16(af[mb], bf[nb], acc[mb][nb], 0, 0, 0); \
        }                                                                                          \
    } while (0)

    float4 e0, e1, o0, o1;
    // prologue: stage tile 0 fully, then put A(1) in flight
    BSTAGE(0, 0);
    __builtin_amdgcn_sched_barrier(0);
    e0 = *(const float4*)(asrc);
    e1 = *(const float4*)(asrc + 4);
    asm volatile("s_waitcnt vmcnt(0)" ::: "memory");
    AWRITE(0, e0, e1);
    __syncthreads();
    o0 = *(const float4*)(asrc + 32);
    o1 = *(const float4*)(asrc + 36);
    __builtin_amdgcn_sched_barrier(0);

    const int NKS = D_ / 32;   // 32 (even)
    for (int ks = 0; ks < NKS; ks += 2) {
        // ===== even step ks: compute buf0; A(ks+1) held in (o0,o1); issue A(ks+2)->(e0,e1)
        BSTAGE(1, (ks + 1) * 32);
        __builtin_amdgcn_sched_barrier(0);   // pin: B-loads before A-loads
        if (ks + 2 < NKS) {
            e0 = *(const float4*)(asrc + (ks + 2) * 32);
            e1 = *(const float4*)(asrc + (ks + 2) * 32 + 4);
        }
        __builtin_amdgcn_sched_barrier(0);   // pin: A-loads issued here, not sunk below
        COMPUTE(0);
        if (ks + 2 < NKS) asm volatile("s_waitcnt vmcnt(2)" ::: "memory");   // A(ks+1)+B(ks+1) done; A(ks+2) in flight
        else              asm volatile("s_waitcnt vmcnt(0)" ::: "memory");
        __builtin_amdgcn_sched_barrier(0);
        AWRITE(1, o0, o1);
        asm volatile("s_waitcnt lgkmcnt(0)" ::: "memory");
        __builtin_amdgcn_s_barrier();
        __builtin_amdgcn_sched_barrier(0);

        // ===== odd step ks+1: compute buf1; A(ks+2) in (e0,e1); issue A(ks+3)->(o0,o1)
        if (ks + 2 < NKS) {
            BSTAGE(0, (ks + 2) * 32);
            __builtin_amdgcn_sched_barrier(0);
            if (ks + 3 < NKS) {
                o0 = *(const float4*)(asrc + (ks + 3) * 32);
                o1 = *(const float4*)(asrc + (ks + 3) * 32 + 4);
            }
            __builtin_amdgcn_sched_barrier(0);
        }
        COMPUTE(1);
        if (ks + 2 < NKS) {
            if (ks + 3 < NKS) asm volatile("s_waitcnt vmcnt(2)" ::: "memory");
            else              asm volatile("s_waitcnt vmcnt(0)" ::: "memory");
            __builtin_amdgcn_sched_barrier(0);
            AWRITE(0, e0, e1);
            asm volatile("s_waitcnt lgkmcnt(0)" ::: "memory");
            __builtin_amdgcn_s_barrier();
            __builtin_amdgcn_sched_barrier(0);
        }
    }
    #undef BSTAGE
    #undef AWRITE
    #undef COMPUTE

    const int h = nt * 4 + wc;
    const int b = Mbase >> 11;
    const int bh = b * H_ + h;
    const int sbase = Mbase & (S_ - 1);
    const float* bias = ((p == 0) ? bq : (p == 1) ? bk : bv) + h * A_;
    const float bsc = (p == 0) ? INV_LN2 : 1.0f;
    #pragma unroll
    for (int mb = 0; mb < 4; mb++) {
        #pragma unroll
        for (int nb = 0; nb < 4; nb++) {
            const int a = nb * 16 + lr;
            const float bia = bias[a] * bsc;
            const int s0 = sbase + wr * 64 + mb * 16 + 4 * lg;
            if (p < 2) {
                uint16_t* o = (p == 0) ? qh : kh;
                #pragma unroll
                for (int r = 0; r < 4; r++)
                    o[(bh * S_ + s0 + r) * A_ + a] = (uint16_t)f2h(acc[mb][nb][r] + bia);
            } else {
                const int kt2 = s0 >> 6, kv0 = s0 & 63;
                const int kb2 = kv0 >> 5, jhi = (kv0 >> 4) & 1, lg2 = (kv0 >> 2) & 3;
                uint2 pk2;
                pk2.x = f2h(acc[mb][nb][0] + bia) | (f2h(acc[mb][nb][1] + bia) << 16);
                pk2.y = f2h(acc[mb][nb][2] + bia) | (f2h(acc[mb][nb][3] + bia) << 16);
                *(uint2*)(vpv + ((size_t)((bh * 32 + kt2) * 512 + kb2 * 256 + lg2 * 64 + a)) * 8 + 4 * jhi) = pk2;
            }
        }
    }
}

// ---------------------------------------------------------------- flash attention
// (R17 best-measured config, unchanged) 512 thr / 8 waves, QBLK=128, KVBLK=64,
// 3-deep rotating K/V (48 KB) with counted vmcnt(2) and ONE raw barrier per tile.
// XCD remap, swapped QK^T with C-init = -m, per-lane defer-check, l-sum via
// ones-MFMA, pkrtz packing, full-line stores via LDS restage.
__global__ __launch_bounds__(512, 8) void flash_kernel(
    const uint16_t* __restrict__ qh, const uint16_t* __restrict__ kh,
    const uint16_t* __restrict__ vpv, float* __restrict__ out)
{
    __shared__ __align__(16) uint16_t smem[24576];   // K[3]: 0..12287 | V[3]: 12288..24575 (u16)
    const int t = threadIdx.x, lane = t & 63, w = t >> 6;   // w: 0..7
    const int lr = lane & 15, lg = lane >> 4;

    // XCD-locality remap: 16 same-bh blocks land on one XCD's L2
    const int flat = blockIdx.y * gridDim.x + blockIdx.x;   // 0..1023
    const int nf = (flat & 7) * 128 + (flat >> 3);
    const int qt = nf & 15, bh = nf >> 4;
    const int b = bh >> 4, h = bh & (H_ - 1);

    // Q as B-fragment: lane (lr,lg) holds Q[q = qt*128 + w*16 + lr][d = kb*32+8*lg+j]
    f16x8 qf[2];
    {
        const uint16_t* qp = qh + (size_t)(bh * S_ + qt * 128 + w * 16 + lr) * A_ + 8 * lg;
        qf[0] = *(const f16x8*)(qp);
        qf[1] = *(const f16x8*)(qp + 32);
    }
    f16x8 ones;
    #pragma unroll
    for (int j = 0; j < 8; j++) ones[j] = (_Float16)1.0f;

    // Staging: 512 lanes x 16 B = one full 8 KB tile per instruction.
    const int row0 = t >> 3;           // 0..63
    const int col0 = (t * 8) & 63;
    const int scol = col0 ^ ((row0 & 7) << 3);
    const uint16_t* kg = kh + (size_t)(bh * S_ + row0) * A_ + scol;
    const uint16_t* vg = vpv + (size_t)bh * (S_ * A_) + t * 8;

    // negm = -m of q-row lr (log2 domain), all 4 comps equal; feeds QK C-init.
    f32x4 negm = {};
    f32x4 oacc[4] = {};
    f32x4 lsum = {};

    #define FSTAGE(buf, kt_) do {                                                         \
        __builtin_amdgcn_global_load_lds(kg + (size_t)(kt_) * (64 * A_),                  \
                                         smem + (buf) * 4096 + w * 512, 16, 0, 0);        \
        __builtin_amdgcn_global_load_lds(vg + (size_t)(kt_) * 4096,                       \
                                         smem + 12288 + (buf) * 4096 + w * 512, 16, 0, 0);\
    } while (0)

    const int NT = S_ / 64;   // 32
    FSTAGE(0, 0);
    FSTAGE(1, 1);

    int cur = 0;
    for (int kt = 0; kt < NT; kt++) {
        if (kt < NT - 1) asm volatile("s_waitcnt vmcnt(2)" ::: "memory");   // tile kt landed; kt+1 in flight
        else             asm volatile("s_waitcnt vmcnt(0)" ::: "memory");
        __builtin_amdgcn_s_barrier();       // everyone's tile kt visible; buf (kt+2)%3 free to overwrite
        __builtin_amdgcn_sched_barrier(0);
        if (kt + 2 < NT) {
            int nb2 = cur + 2; if (nb2 >= 3) nb2 -= 3;
            FSTAGE(nb2, kt + 2);
        }
        __builtin_amdgcn_sched_barrier(0);
        const uint16_t* Kc = smem + cur * 4096;
        const uint16_t* Vc = smem + 12288 + cur * 4096;

        // QK^T swapped; C-init = negm: sacc[nb] = s(kv = nb*16+4*lg+r, q = lr) - m
        f32x4 sacc[4];
        __builtin_amdgcn_s_setprio(1);
        #pragma unroll
        for (int nb = 0; nb < 4; nb++) {
            f16x8 kf = *(const f16x8*)(Kc + swz(nb * 16 + lr, 8 * lg));
            sacc[nb] = __builtin_amdgcn_mfma_f32_16x16x32_f16(kf, qf[0], negm, 0, 0, 0);
        }
        #pragma unroll
        for (int nb = 0; nb < 4; nb++) {
            f16x8 kf = *(const f16x8*)(Kc + swz(nb * 16 + lr, 32 + 8 * lg));
            sacc[nb] = __builtin_amdgcn_mfma_f32_16x16x32_f16(kf, qf[1], sacc[nb], 0, 0, 0);
        }
        __builtin_amdgcn_s_setprio(0);

        // per-lane max over own 16 scores (no cross-lane reduce on the fast path)
        float a0 = fmaxf(fmaxf(sacc[0][0], sacc[0][1]), sacc[0][2]);
        float a1 = fmaxf(fmaxf(sacc[0][3], sacc[1][0]), sacc[1][1]);
        float a2 = fmaxf(fmaxf(sacc[1][2], sacc[1][3]), sacc[2][0]);
        float a3 = fmaxf(fmaxf(sacc[2][1], sacc[2][2]), sacc[2][3]);
        float a4 = fmaxf(fmaxf(sacc[3][0], sacc[3][1]), sacc[3][2]);
        float pm = fmaxf(fmaxf(fmaxf(a0, a1), fmaxf(a2, a3)), fmaxf(a4, sacc[3][3]));

        // defer-max: rescale only when some row grew past m+11 (P <= 2^11 < f16 max)
        if (__any(pm > 11.0f)) {
            float tm = fmaxf(pm, __shfl_xor(pm, 16));
            tm = fmaxf(tm, __shfl_xor(tm, 32));
            float delta = fmaxf(tm, 0.0f);
            float sc = exp2f_fast(-delta);
            #pragma unroll
            for (int r = 0; r < 4; r++) negm[r] -= delta;
            #pragma unroll
            for (int nb = 0; nb < 4; nb++) {
                #pragma unroll
                for (int r = 0; r < 4; r++) sacc[nb][r] -= delta;
            }
            float scr[4];
            #pragma unroll
            for (int r = 0; r < 4; r++) scr[r] = __shfl(sc, 4 * lg + r);
            #pragma unroll
            for (int r = 0; r < 4; r++) lsum[r] *= scr[r];
            #pragma unroll
            for (int nb = 0; nb < 4; nb++) {
                #pragma unroll
                for (int r = 0; r < 4; r++) oacc[nb][r] *= scr[r];
            }
        }

        // P = exp2(sacc) packed (pkrtz) directly into PV A-fragments
        f16x8 paf[2];
        #pragma unroll
        for (int kb2 = 0; kb2 < 2; kb2++) {
            float e[8];
            #pragma unroll
            for (int jh = 0; jh < 2; jh++) {
                #pragma unroll
                for (int r = 0; r < 4; r++)
                    e[jh * 4 + r] = exp2f_fast(sacc[2 * kb2 + jh][r]);
            }
            uint4 u;
            u.x = pkrtz(e[0], e[1]); u.y = pkrtz(e[2], e[3]);
            u.z = pkrtz(e[4], e[5]); u.w = pkrtz(e[6], e[7]);
            paf[kb2] = __builtin_bit_cast(f16x8, u);
        }

        // l-sum via ones-MFMA (row sums land in oacc row layout) + PV
        __builtin_amdgcn_s_setprio(1);
        lsum = __builtin_amdgcn_mfma_f32_16x16x32_f16(paf[0], ones, lsum, 0, 0, 0);
        lsum = __builtin_amdgcn_mfma_f32_16x16x32_f16(paf[1], ones, lsum, 0, 0, 0);
        #pragma unroll
        for (int kb2 = 0; kb2 < 2; kb2++) {
            #pragma unroll
            for (int nb = 0; nb < 4; nb++) {
                f16x8 vf = *(const f16x8*)(Vc + ((kb2 * 4 + lg) * 64 + nb * 16 + lr) * 8);
                oacc[nb] = __builtin_amdgcn_mfma_f32_16x16x32_f16(paf[kb2], vf, oacc[nb], 0, 0, 0);
            }
        }
        __builtin_amdgcn_s_setprio(0);

        cur = (cur == 2) ? 0 : cur + 1;
    }
    #undef FSTAGE

    // normalize into LDS (reusing K/V space), then full-line coalesced stores
    __syncthreads();   // all waves done with K/V LDS
    float* outs = (float*)smem;   // 128 x 64 f32 = 32 KB
    #pragma unroll
    for (int r = 0; r < 4; r++) {
        const float inv = 1.0f / lsum[r];
        const int sl = w * 16 + 4 * lg + r;
        #pragma unroll
        for (int nb = 0; nb < 4; nb++)
            outs[sl * 64 + nb * 16 + lr] = oacc[nb][r] * inv;
    }
    __syncthreads();
    const int orow = t >> 4, oslot = t & 15;
    float* obase = out + (size_t)(b * S_ + qt * 128 + orow) * (H_ * A_) + h * A_ + oslot * 4;
    #pragma unroll
    for (int i = 0; i < 4; i++)
        *(float4*)(obase + (size_t)(32 * i) * (H_ * A_)) =
            *(const float4*)(outs + (orow + 32 * i) * 64 + oslot * 4);
}

// ----------------------------------------------------------------
extern "C" void kernel_launch(void* const* d_in, const int* in_sizes, int n_in,
                              void* d_out, int out_size, void* d_ws, size_t ws_size,
                              hipStream_t stream)
{
    const float* q  = (const float*)d_in[0];
    const float* k  = (const float*)d_in[1];
    const float* v  = (const float*)d_in[2];
    const float* Wq = (const float*)d_in[3];
    const float* bq = (const float*)d_in[4];
    const float* Wk = (const float*)d_in[5];
    const float* bk = (const float*)d_in[6];
    const float* Wv = (const float*)d_in[7];
    const float* bv = (const float*)d_in[8];
    float* out = (float*)d_out;

    uint8_t* ws = (uint8_t*)d_ws;
    const size_t SZ_H  = (size_t)BH_ * S_ * A_ * 2;     // 16 MB each
    uint16_t* qh  = (uint16_t*)(ws);
    uint16_t* kh  = (uint16_t*)(ws + SZ_H);
    uint16_t* vpv = (uint16_t*)(ws + 2 * SZ_H);
    uint16_t* Wt  = (uint16_t*)(ws + 3 * SZ_H);

    prep_w<<<dim3(16, H_, 3), 256, 0, stream>>>(Wq, Wk, Wv, Wt);
    proj_kernel<<<dim3(M_ / 128, 4, 3), 512, 0, stream>>>(q, k, v, Wt,
                                                          bq, bk, bv, qh, kh, vpv);
    flash_kernel<<<dim3(S_ / 128, BH_), 512, 0, stream>>>(qh, kh, vpv, out);
}

// Round 21
// 159.676 us; speedup vs baseline: 1.1699x; 1.0408x over previous
//
#include <hip/hip_runtime.h>
#include <stdint.h>

#define B_ 4
#define S_ 2048
#define D_ 1024
#define H_ 16
#define A_ 64
#define M_ (B_*S_)    // 8192
#define BH_ (B_*H_)   // 64
#define INV_LN2 1.4426950408889634f

typedef _Float16 f16x8 __attribute__((ext_vector_type(8)));
typedef float    f32x4 __attribute__((ext_vector_type(4)));

__device__ __forceinline__ uint32_t f2h(float f) {
    _Float16 h = (_Float16)f;                      // RNE
    return (uint32_t)__builtin_bit_cast(uint16_t, h);
}

__device__ __forceinline__ float exp2f_fast(float x) {
    return __builtin_amdgcn_exp2f(x);              // v_exp_f32: computes 2^x
}

__device__ __forceinline__ uint32_t pkrtz(float a, float b) {
    return __builtin_bit_cast(uint32_t, __builtin_amdgcn_cvt_pkrtz(a, b));
}

// XOR swizzle for [R][64]-f16 LDS tiles (row stride 128 B)
__device__ __forceinline__ int swz(int row, int col) {
    return (row * 64 + col) ^ ((row & 7) << 3);
}

// ---------------------------------------------------------------- prep: W -> Wt[p][h][a][d] f16
// p==0 (Wq) additionally scaled by 1/ln2 so QK^T scores land in log2 domain.
__global__ __launch_bounds__(256) void prep_w(
    const float* __restrict__ Wq, const float* __restrict__ Wk, const float* __restrict__ Wv,
    uint16_t* __restrict__ Wt)
{
    __shared__ float tile[64][65];
    const int dt = blockIdx.x, h = blockIdx.y, p = blockIdx.z;
    const float* W = (p == 0) ? Wq : (p == 1) ? Wk : Wv;
    const float sc = (p == 0) ? INV_LN2 : 1.0f;
    const float* src = W + (h * D_ + dt * 64) * A_;   // [64 d][64 a]
    const int t = threadIdx.x;
    const int r0 = t >> 4, c4 = (t & 15) * 4;
    #pragma unroll
    for (int i = 0; i < 4; i++) {
        int r = r0 + i * 16;
        float4 x = *(const float4*)(src + r * A_ + c4);
        tile[r][c4] = x.x; tile[r][c4 + 1] = x.y; tile[r][c4 + 2] = x.z; tile[r][c4 + 3] = x.w;
    }
    __syncthreads();
    uint16_t* dst = Wt + (p * H_ + h) * (A_ * D_) + dt * 64;
    #pragma unroll
    for (int i = 0; i < 4; i++) {
        int a = r0 + i * 16;
        int d4 = (t & 15) * 4;
        uint2 o2;
        o2.x = f2h(tile[d4][a] * sc)     | (f2h(tile[d4 + 1][a] * sc) << 16);
        o2.y = f2h(tile[d4 + 2][a] * sc) | (f2h(tile[d4 + 3][a] * sc) << 16);
        *(uint2*)(dst + a * D_ + d4) = o2;
    }
}

// ---------------------------------------------------------------- projection GEMM
// (R20 best config, unchanged) Fused f32 input, BK=32, 48 KB dbuf, 2-step A
// prefetch with counted vmcnt + raw barriers.
__global__ __launch_bounds__(512) void proj_kernel(
    const float* __restrict__ qsrc, const float* __restrict__ ksrc, const float* __restrict__ vsrc,
    const uint16_t* __restrict__ Wt,
    const float* __restrict__ bq, const float* __restrict__ bk, const float* __restrict__ bv,
    uint16_t* __restrict__ qh, uint16_t* __restrict__ kh, uint16_t* __restrict__ vpv)
{
    __shared__ __align__(16) uint16_t As[2][128 * 32];   // 2 x 8 KB
    __shared__ __align__(16) uint16_t Bs[2][256 * 32];   // 2 x 16 KB  rows: h'*64 + a
    const int p = blockIdx.z, nt = blockIdx.y, mt = blockIdx.x;
    const int t = threadIdx.x, lane = t & 63, w = t >> 6;
    const int wr = w >> 2, wc = w & 3;
    const int lr = lane & 15, lg = lane >> 4;
    const int Mbase = mt * 128;
    const float* Af = (p == 0) ? qsrc : (p == 1) ? ksrc : vsrc;

    const int ar  = t >> 2;
    const int als = t & 3;
    const int afx = (ar >> 1) & 3;                       // f(row)
    const float* asrc = Af + (size_t)(Mbase + ar) * D_ + als * 8;
    const int awoff = ar * 32 + ((als ^ afx) * 8);       // phys slot = logical ^ f(row)

    const int bslot = (t & 3) ^ (((t >> 2) >> 1) & 3);
    const uint16_t* bsrc0 = Wt + ((size_t)(p * H_ + nt * 4 + ((t >> 2) >> 6)) * A_ + ((t >> 2) & 63)) * D_ + bslot * 8;
    const uint16_t* bsrc1 = Wt + ((size_t)(p * H_ + nt * 4 + (((t >> 2) + 128) >> 6)) * A_ + ((t >> 2) & 63)) * D_ + bslot * 8;

    f32x4 acc[4][4] = {};

    #define BSTAGE(buf, kkv) do {                                                                  \
        __builtin_amdgcn_global_load_lds(bsrc0 + (kkv), (char*)(&Bs[buf][0]) + w * 1024,        16, 0, 0); \
        __builtin_amdgcn_global_load_lds(bsrc1 + (kkv), (char*)(&Bs[buf][0]) + 8192 + w * 1024, 16, 0, 0); \
    } while (0)

    #define AWRITE(buf, v0, v1) do {                                                               \
        uint4 u_;                                                                                  \
        u_.x = pkrtz((v0).x, (v0).y); u_.y = pkrtz((v0).z, (v0).w);                                \
        u_.z = pkrtz((v1).x, (v1).y); u_.w = pkrtz((v1).z, (v1).w);                                \
        *(uint4*)(&As[buf][awoff]) = u_;                                                           \
    } while (0)

    #define COMPUTE(buf) do {                                                                      \
        f16x8 af[4], bf[4];                                                                        \
        _Pragma("unroll")                                                                          \
        for (int mb = 0; mb < 4; mb++) {                                                           \
            const int r = wr * 64 + mb * 16 + lr;                                                  \
            af[mb] = *(const f16x8*)(&As[buf][r * 32 + ((lg ^ ((r >> 1) & 3)) * 8)]);              \
        }                                                                                          \
        _Pragma("unroll")                                                                          \
        for (int nb = 0; nb < 4; nb++) {                                                           \
            const int r = wc * 64 + nb * 16 + lr;                                                  \
            bf[nb] = *(const f16x8*)(&Bs[buf][r * 32 + ((lg ^ ((r >> 1) & 3)) * 8)]);              \
        }                                                                                          \
        _Pragma("unroll")                                                                          \
        for (int mb = 0; mb < 4; mb++) {                                                           \
            _Pragma("unroll")                                                                      \
            for (int nb = 0; nb < 4; nb++)                                                         \
                acc[mb][nb] = __builtin_amdgcn_mfma_f32_16x16x32_f16(af[mb], bf[nb], acc[mb][nb], 0, 0, 0); \
        }                                                                                          \
    } while (0)

    float4 e0, e1, o0, o1;
    BSTAGE(0, 0);
    __builtin_amdgcn_sched_barrier(0);
    e0 = *(const float4*)(asrc);
    e1 = *(const float4*)(asrc + 4);
    asm volatile("s_waitcnt vmcnt(0)" ::: "memory");
    AWRITE(0, e0, e1);
    __syncthreads();
    o0 = *(const float4*)(asrc + 32);
    o1 = *(const float4*)(asrc + 36);
    __builtin_amdgcn_sched_barrier(0);

    const int NKS = D_ / 32;   // 32 (even)
    for (int ks = 0; ks < NKS; ks += 2) {
        BSTAGE(1, (ks + 1) * 32);
        __builtin_amdgcn_sched_barrier(0);
        if (ks + 2 < NKS) {
            e0 = *(const float4*)(asrc + (ks + 2) * 32);
            e1 = *(const float4*)(asrc + (ks + 2) * 32 + 4);
        }
        __builtin_amdgcn_sched_barrier(0);
        COMPUTE(0);
        if (ks + 2 < NKS) asm volatile("s_waitcnt vmcnt(2)" ::: "memory");
        else              asm volatile("s_waitcnt vmcnt(0)" ::: "memory");
        __builtin_amdgcn_sched_barrier(0);
        AWRITE(1, o0, o1);
        asm volatile("s_waitcnt lgkmcnt(0)" ::: "memory");
        __builtin_amdgcn_s_barrier();
        __builtin_amdgcn_sched_barrier(0);

        if (ks + 2 < NKS) {
            BSTAGE(0, (ks + 2) * 32);
            __builtin_amdgcn_sched_barrier(0);
            if (ks + 3 < NKS) {
                o0 = *(const float4*)(asrc + (ks + 3) * 32);
                o1 = *(const float4*)(asrc + (ks + 3) * 32 + 4);
            }
            __builtin_amdgcn_sched_barrier(0);
        }
        COMPUTE(1);
        if (ks + 2 < NKS) {
            if (ks + 3 < NKS) asm volatile("s_waitcnt vmcnt(2)" ::: "memory");
            else              asm volatile("s_waitcnt vmcnt(0)" ::: "memory");
            __builtin_amdgcn_sched_barrier(0);
            AWRITE(0, e0, e1);
            asm volatile("s_waitcnt lgkmcnt(0)" ::: "memory");
            __builtin_amdgcn_s_barrier();
            __builtin_amdgcn_sched_barrier(0);
        }
    }
    #undef BSTAGE
    #undef AWRITE
    #undef COMPUTE

    const int h = nt * 4 + wc;
    const int b = Mbase >> 11;
    const int bh = b * H_ + h;
    const int sbase = Mbase & (S_ - 1);
    const float* bias = ((p == 0) ? bq : (p == 1) ? bk : bv) + h * A_;
    const float bsc = (p == 0) ? INV_LN2 : 1.0f;
    #pragma unroll
    for (int mb = 0; mb < 4; mb++) {
        #pragma unroll
        for (int nb = 0; nb < 4; nb++) {
            const int a = nb * 16 + lr;
            const float bia = bias[a] * bsc;
            const int s0 = sbase + wr * 64 + mb * 16 + 4 * lg;
            if (p < 2) {
                uint16_t* o = (p == 0) ? qh : kh;
                #pragma unroll
                for (int r = 0; r < 4; r++)
                    o[(bh * S_ + s0 + r) * A_ + a] = (uint16_t)f2h(acc[mb][nb][r] + bia);
            } else {
                const int kt2 = s0 >> 6, kv0 = s0 & 63;
                const int kb2 = kv0 >> 5, jhi = (kv0 >> 4) & 1, lg2 = (kv0 >> 2) & 3;
                uint2 pk2;
                pk2.x = f2h(acc[mb][nb][0] + bia) | (f2h(acc[mb][nb][1] + bia) << 16);
                pk2.y = f2h(acc[mb][nb][2] + bia) | (f2h(acc[mb][nb][3] + bia) << 16);
                *(uint2*)(vpv + ((size_t)((bh * 32 + kt2) * 512 + kb2 * 256 + lg2 * 64 + a)) * 8 + 4 * jhi) = pk2;
            }
        }
    }
}

// ---------------------------------------------------------------- flash attention
// QBLK=256: each wave owns TWO independent 16-row groups (g=0,1) sharing the
// K/V stage -> 36 MFMA + 2x softmax per wait+barrier (halves sync overhead per
// unit work). Group-SERIAL QK->softmax->paf caps live VGPR (~110).
// launch_bounds(512,4): 16 waves/CU = 2 blocks/CU; grid 512 = exactly 2/CU
// (zero tail). 3-deep rotating K/V (48 KB), counted vmcnt(2), one barrier/tile,
// XCD remap (8 bh per XCD, all 8 qt local), l-sum via ones-MFMA, pkrtz,
// full-line stores via two-pass LDS restage.
__global__ __launch_bounds__(512, 4) void flash_kernel(
    const uint16_t* __restrict__ qh, const uint16_t* __restrict__ kh,
    const uint16_t* __restrict__ vpv, float* __restrict__ out)
{
    __shared__ __align__(16) uint16_t smem[24576];   // K[3]: 0..12287 | V[3]: 12288..24575 (u16)
    const int t = threadIdx.x, lane = t & 63, w = t >> 6;   // w: 0..7
    const int lr = lane & 15, lg = lane >> 4;

    // XCD-locality remap: 8 same-XCD bh's, each with all 8 qt tiles
    const int flat = blockIdx.x;                     // 0..511
    const int nf = (flat & 7) * 64 + (flat >> 3);
    const int qt = nf & 7, bh = nf >> 3;
    const int b = bh >> 4, h = bh & (H_ - 1);

    // Q as B-fragment, two groups: rows qt*256 + g*128 + w*16 + lr
    f16x8 qf0[2], qf1[2];
    {
        const uint16_t* qp0 = qh + (size_t)(bh * S_ + qt * 256 + w * 16 + lr) * A_ + 8 * lg;
        qf0[0] = *(const f16x8*)(qp0);
        qf0[1] = *(const f16x8*)(qp0 + 32);
        const uint16_t* qp1 = qp0 + (size_t)128 * A_;
        qf1[0] = *(const f16x8*)(qp1);
        qf1[1] = *(const f16x8*)(qp1 + 32);
    }
    f16x8 ones;
    #pragma unroll
    for (int j = 0; j < 8; j++) ones[j] = (_Float16)1.0f;

    // Staging: 512 lanes x 16 B = one full 8 KB tile per instruction.
    const int row0 = t >> 3;           // 0..63
    const int col0 = (t * 8) & 63;
    const int scol = col0 ^ ((row0 & 7) << 3);
    const uint16_t* kg = kh + (size_t)(bh * S_ + row0) * A_ + scol;
    const uint16_t* vg = vpv + (size_t)bh * (S_ * A_) + t * 8;

    f32x4 negm0 = {}, negm1 = {};
    f32x4 oacc0[4] = {}, oacc1[4] = {};
    f32x4 lsum0 = {}, lsum1 = {};

    #define FSTAGE(buf, kt_) do {                                                         \
        __builtin_amdgcn_global_load_lds(kg + (size_t)(kt_) * (64 * A_),                  \
                                         smem + (buf) * 4096 + w * 512, 16, 0, 0);        \
        __builtin_amdgcn_global_load_lds(vg + (size_t)(kt_) * 4096,                       \
                                         smem + 12288 + (buf) * 4096 + w * 512, 16, 0, 0);\
    } while (0)

    const int NT = S_ / 64;   // 32
    FSTAGE(0, 0);
    FSTAGE(1, 1);

    int cur = 0;
    for (int kt = 0; kt < NT; kt++) {
        if (kt < NT - 1) asm volatile("s_waitcnt vmcnt(2)" ::: "memory");
        else             asm volatile("s_waitcnt vmcnt(0)" ::: "memory");
        __builtin_amdgcn_s_barrier();
        __builtin_amdgcn_sched_barrier(0);
        if (kt + 2 < NT) {
            int nb2 = cur + 2; if (nb2 >= 3) nb2 -= 3;
            FSTAGE(nb2, kt + 2);
        }
        __builtin_amdgcn_sched_barrier(0);
        const uint16_t* Kc = smem + cur * 4096;
        const uint16_t* Vc = smem + 12288 + cur * 4096;

        f16x8 paf0[2], paf1[2];

        // ===== group 0: QK -> softmax -> paf -> lsum
        {
            f32x4 sacc[4];
            __builtin_amdgcn_s_setprio(1);
            #pragma unroll
            for (int nb = 0; nb < 4; nb++) {
                f16x8 kf = *(const f16x8*)(Kc + swz(nb * 16 + lr, 8 * lg));
                sacc[nb] = __builtin_amdgcn_mfma_f32_16x16x32_f16(kf, qf0[0], negm0, 0, 0, 0);
            }
            #pragma unroll
            for (int nb = 0; nb < 4; nb++) {
                f16x8 kf = *(const f16x8*)(Kc + swz(nb * 16 + lr, 32 + 8 * lg));
                sacc[nb] = __builtin_amdgcn_mfma_f32_16x16x32_f16(kf, qf0[1], sacc[nb], 0, 0, 0);
            }
            __builtin_amdgcn_s_setprio(0);
            float a0 = fmaxf(fmaxf(sacc[0][0], sacc[0][1]), sacc[0][2]);
            float a1 = fmaxf(fmaxf(sacc[0][3], sacc[1][0]), sacc[1][1]);
            float a2 = fmaxf(fmaxf(sacc[1][2], sacc[1][3]), sacc[2][0]);
            float a3 = fmaxf(fmaxf(sacc[2][1], sacc[2][2]), sacc[2][3]);
            float a4 = fmaxf(fmaxf(sacc[3][0], sacc[3][1]), sacc[3][2]);
            float pm = fmaxf(fmaxf(fmaxf(a0, a1), fmaxf(a2, a3)), fmaxf(a4, sacc[3][3]));
            if (__any(pm > 11.0f)) {
                float tm = fmaxf(pm, __shfl_xor(pm, 16));
                tm = fmaxf(tm, __shfl_xor(tm, 32));
                float delta = fmaxf(tm, 0.0f);
                float sc = exp2f_fast(-delta);
                #pragma unroll
                for (int r = 0; r < 4; r++) negm0[r] -= delta;
                #pragma unroll
                for (int nb = 0; nb < 4; nb++) {
                    #pragma unroll
                    for (int r = 0; r < 4; r++) sacc[nb][r] -= delta;
                }
                float scr[4];
                #pragma unroll
                for (int r = 0; r < 4; r++) scr[r] = __shfl(sc, 4 * lg + r);
                #pragma unroll
                for (int r = 0; r < 4; r++) lsum0[r] *= scr[r];
                #pragma unroll
                for (int nb = 0; nb < 4; nb++) {
                    #pragma unroll
                    for (int r = 0; r < 4; r++) oacc0[nb][r] *= scr[r];
                }
            }
            #pragma unroll
            for (int kb2 = 0; kb2 < 2; kb2++) {
                float e[8];
                #pragma unroll
                for (int jh = 0; jh < 2; jh++)
                    #pragma unroll
                    for (int r = 0; r < 4; r++)
                        e[jh * 4 + r] = exp2f_fast(sacc[2 * kb2 + jh][r]);
                uint4 u;
                u.x = pkrtz(e[0], e[1]); u.y = pkrtz(e[2], e[3]);
                u.z = pkrtz(e[4], e[5]); u.w = pkrtz(e[6], e[7]);
                paf0[kb2] = __builtin_bit_cast(f16x8, u);
            }
            lsum0 = __builtin_amdgcn_mfma_f32_16x16x32_f16(paf0[0], ones, lsum0, 0, 0, 0);
            lsum0 = __builtin_amdgcn_mfma_f32_16x16x32_f16(paf0[1], ones, lsum0, 0, 0, 0);
        }

        // ===== group 1: QK -> softmax -> paf -> lsum
        {
            f32x4 sacc[4];
            __builtin_amdgcn_s_setprio(1);
            #pragma unroll
            for (int nb = 0; nb < 4; nb++) {
                f16x8 kf = *(const f16x8*)(Kc + swz(nb * 16 + lr, 8 * lg));
                sacc[nb] = __builtin_amdgcn_mfma_f32_16x16x32_f16(kf, qf1[0], negm1, 0, 0, 0);
            }
            #pragma unroll
            for (int nb = 0; nb < 4; nb++) {
                f16x8 kf = *(const f16x8*)(Kc + swz(nb * 16 + lr, 32 + 8 * lg));
                sacc[nb] = __builtin_amdgcn_mfma_f32_16x16x32_f16(kf, qf1[1], sacc[nb], 0, 0, 0);
            }
            __builtin_amdgcn_s_setprio(0);
            float a0 = fmaxf(fmaxf(sacc[0][0], sacc[0][1]), sacc[0][2]);
            float a1 = fmaxf(fmaxf(sacc[0][3], sacc[1][0]), sacc[1][1]);
            float a2 = fmaxf(fmaxf(sacc[1][2], sacc[1][3]), sacc[2][0]);
            float a3 = fmaxf(fmaxf(sacc[2][1], sacc[2][2]), sacc[2][3]);
            float a4 = fmaxf(fmaxf(sacc[3][0], sacc[3][1]), sacc[3][2]);
            float pm = fmaxf(fmaxf(fmaxf(a0, a1), fmaxf(a2, a3)), fmaxf(a4, sacc[3][3]));
            if (__any(pm > 11.0f)) {
                float tm = fmaxf(pm, __shfl_xor(pm, 16));
                tm = fmaxf(tm, __shfl_xor(tm, 32));
                float delta = fmaxf(tm, 0.0f);
                float sc = exp2f_fast(-delta);
                #pragma unroll
                for (int r = 0; r < 4; r++) negm1[r] -= delta;
                #pragma unroll
                for (int nb = 0; nb < 4; nb++) {
                    #pragma unroll
                    for (int r = 0; r < 4; r++) sacc[nb][r] -= delta;
                }
                float scr[4];
                #pragma unroll
                for (int r = 0; r < 4; r++) scr[r] = __shfl(sc, 4 * lg + r);
                #pragma unroll
                for (int r = 0; r < 4; r++) lsum1[r] *= scr[r];
                #pragma unroll
                for (int nb = 0; nb < 4; nb++) {
                    #pragma unroll
                    for (int r = 0; r < 4; r++) oacc1[nb][r] *= scr[r];
                }
            }
            #pragma unroll
            for (int kb2 = 0; kb2 < 2; kb2++) {
                float e[8];
                #pragma unroll
                for (int jh = 0; jh < 2; jh++)
                    #pragma unroll
                    for (int r = 0; r < 4; r++)
                        e[jh * 4 + r] = exp2f_fast(sacc[2 * kb2 + jh][r]);
                uint4 u;
                u.x = pkrtz(e[0], e[1]); u.y = pkrtz(e[2], e[3]);
                u.z = pkrtz(e[4], e[5]); u.w = pkrtz(e[6], e[7]);
                paf1[kb2] = __builtin_bit_cast(f16x8, u);
            }
            lsum1 = __builtin_amdgcn_mfma_f32_16x16x32_f16(paf1[0], ones, lsum1, 0, 0, 0);
            lsum1 = __builtin_amdgcn_mfma_f32_16x16x32_f16(paf1[1], ones, lsum1, 0, 0, 0);
        }

        // ===== PV both groups (vf shared)
        __builtin_amdgcn_s_setprio(1);
        #pragma unroll
        for (int kb2 = 0; kb2 < 2; kb2++) {
            #pragma unroll
            for (int nb = 0; nb < 4; nb++) {
                f16x8 vf = *(const f16x8*)(Vc + ((kb2 * 4 + lg) * 64 + nb * 16 + lr) * 8);
                oacc0[nb] = __builtin_amdgcn_mfma_f32_16x16x32_f16(paf0[kb2], vf, oacc0[nb], 0, 0, 0);
                oacc1[nb] = __builtin_amdgcn_mfma_f32_16x16x32_f16(paf1[kb2], vf, oacc1[nb], 0, 0, 0);
            }
        }
        __builtin_amdgcn_s_setprio(0);

        cur = (cur == 2) ? 0 : cur + 1;
    }
    #undef FSTAGE

    // normalize + store, two passes through 32 KB LDS restage
    float* outs = (float*)smem;   // 128 x 64 f32 = 32 KB
    const int orow = t >> 4, oslot = t & 15;
    #pragma unroll
    for (int g = 0; g < 2; g++) {
        __syncthreads();   // all waves done with K/V LDS (g=0) / prev restage (g=1)
        #pragma unroll
        for (int r = 0; r < 4; r++) {
            const int sl = w * 16 + 4 * lg + r;
            if (g == 0) {
                const float inv = 1.0f / lsum0[r];
                #pragma unroll
                for (int nb = 0; nb < 4; nb++)
                    outs[sl * 64 + nb * 16 + lr] = oacc0[nb][r] * inv;
            } else {
                const float inv = 1.0f / lsum1[r];
                #pragma unroll
                for (int nb = 0; nb < 4; nb++)
                    outs[sl * 64 + nb * 16 + lr] = oacc1[nb][r] * inv;
            }
        }
        __syncthreads();
        float* obase = out + (size_t)(b * S_ + qt * 256 + g * 128 + orow) * (H_ * A_) + h * A_ + oslot * 4;
        #pragma unroll
        for (int i = 0; i < 4; i++)
            *(float4*)(obase + (size_t)(32 * i) * (H_ * A_)) =
                *(const float4*)(outs + (orow + 32 * i) * 64 + oslot * 4);
    }
}

// ----------------------------------------------------------------
extern "C" void kernel_launch(void* const* d_in, const int* in_sizes, int n_in,
                              void* d_out, int out_size, void* d_ws, size_t ws_size,
                              hipStream_t stream)
{
    const float* q  = (const float*)d_in[0];
    const float* k  = (const float*)d_in[1];
    const float* v  = (const float*)d_in[2];
    const float* Wq = (const float*)d_in[3];
    const float* bq = (const float*)d_in[4];
    const float* Wk = (const float*)d_in[5];
    const float* bk = (const float*)d_in[6];
    const float* Wv = (const float*)d_in[7];
    const float* bv = (const float*)d_in[8];
    float* out = (float*)d_out;

    uint8_t* ws = (uint8_t*)d_ws;
    const size_t SZ_H  = (size_t)BH_ * S_ * A_ * 2;     // 16 MB each
    uint16_t* qh  = (uint16_t*)(ws);
    uint16_t* kh  = (uint16_t*)(ws + SZ_H);
    uint16_t* vpv = (uint16_t*)(ws + 2 * SZ_H);
    uint16_t* Wt  = (uint16_t*)(ws + 3 * SZ_H);

    prep_w<<<dim3(16, H_, 3), 256, 0, stream>>>(Wq, Wk, Wv, Wt);
    proj_kernel<<<dim3(M_ / 128, 4, 3), 512, 0, stream>>>(q, k, v, Wt,
                                                          bq, bk, bv, qh, kh, vpv);
    flash_kernel<<<dim3(S_ / 256 * BH_), 512, 0, stream>>>(qh, kh, vpv, out);
}

// Round 22
// 159.643 us; speedup vs baseline: 1.1701x; 1.0002x over previous
//
#include <hip/hip_runtime.h>
#include <stdint.h>

#define B_ 4
#define S_ 2048
#define D_ 1024
#define H_ 16
#define A_ 64
#define M_ (B_*S_)    // 8192
#define BH_ (B_*H_)   // 64
#define INV_LN2 1.4426950408889634f

typedef _Float16 f16x8 __attribute__((ext_vector_type(8)));
typedef float    f32x4 __attribute__((ext_vector_type(4)));

__device__ __forceinline__ uint32_t f2h(float f) {
    _Float16 h = (_Float16)f;                      // RNE
    return (uint32_t)__builtin_bit_cast(uint16_t, h);
}

__device__ __forceinline__ float exp2f_fast(float x) {
    return __builtin_amdgcn_exp2f(x);              // v_exp_f32: computes 2^x
}

__device__ __forceinline__ uint32_t pkrtz(float a, float b) {
    return __builtin_bit_cast(uint32_t, __builtin_amdgcn_cvt_pkrtz(a, b));
}

// XOR swizzle for [R][64]-f16 LDS tiles (row stride 128 B)
__device__ __forceinline__ int swz(int row, int col) {
    return (row * 64 + col) ^ ((row & 7) << 3);
}

// ---------------------------------------------------------------- prep: W -> Wt[p][h][a][d] f16
// p==0 (Wq) additionally scaled by 1/ln2 so QK^T scores land in log2 domain.
__global__ __launch_bounds__(256) void prep_w(
    const float* __restrict__ Wq, const float* __restrict__ Wk, const float* __restrict__ Wv,
    uint16_t* __restrict__ Wt)
{
    __shared__ float tile[64][65];
    const int dt = blockIdx.x, h = blockIdx.y, p = blockIdx.z;
    const float* W = (p == 0) ? Wq : (p == 1) ? Wk : Wv;
    const float sc = (p == 0) ? INV_LN2 : 1.0f;
    const float* src = W + (h * D_ + dt * 64) * A_;   // [64 d][64 a]
    const int t = threadIdx.x;
    const int r0 = t >> 4, c4 = (t & 15) * 4;
    #pragma unroll
    for (int i = 0; i < 4; i++) {
        int r = r0 + i * 16;
        float4 x = *(const float4*)(src + r * A_ + c4);
        tile[r][c4] = x.x; tile[r][c4 + 1] = x.y; tile[r][c4 + 2] = x.z; tile[r][c4 + 3] = x.w;
    }
    __syncthreads();
    uint16_t* dst = Wt + (p * H_ + h) * (A_ * D_) + dt * 64;
    #pragma unroll
    for (int i = 0; i < 4; i++) {
        int a = r0 + i * 16;
        int d4 = (t & 15) * 4;
        uint2 o2;
        o2.x = f2h(tile[d4][a] * sc)     | (f2h(tile[d4 + 1][a] * sc) << 16);
        o2.y = f2h(tile[d4 + 2][a] * sc) | (f2h(tile[d4 + 3][a] * sc) << 16);
        *(uint2*)(dst + a * D_ + d4) = o2;
    }
}

// ---------------------------------------------------------------- projection GEMM
// (R20 best config, unchanged) Fused f32 input, BK=32, 48 KB dbuf, 2-step A
// prefetch with counted vmcnt + raw barriers.
__global__ __launch_bounds__(512) void proj_kernel(
    const float* __restrict__ qsrc, const float* __restrict__ ksrc, const float* __restrict__ vsrc,
    const uint16_t* __restrict__ Wt,
    const float* __restrict__ bq, const float* __restrict__ bk, const float* __restrict__ bv,
    uint16_t* __restrict__ qh, uint16_t* __restrict__ kh, uint16_t* __restrict__ vpv)
{
    __shared__ __align__(16) uint16_t As[2][128 * 32];   // 2 x 8 KB
    __shared__ __align__(16) uint16_t Bs[2][256 * 32];   // 2 x 16 KB  rows: h'*64 + a
    const int p = blockIdx.z, nt = blockIdx.y, mt = blockIdx.x;
    const int t = threadIdx.x, lane = t & 63, w = t >> 6;
    const int wr = w >> 2, wc = w & 3;
    const int lr = lane & 15, lg = lane >> 4;
    const int Mbase = mt * 128;
    const float* Af = (p == 0) ? qsrc : (p == 1) ? ksrc : vsrc;

    const int ar  = t >> 2;
    const int als = t & 3;
    const int afx = (ar >> 1) & 3;                       // f(row)
    const float* asrc = Af + (size_t)(Mbase + ar) * D_ + als * 8;
    const int awoff = ar * 32 + ((als ^ afx) * 8);       // phys slot = logical ^ f(row)

    const int bslot = (t & 3) ^ (((t >> 2) >> 1) & 3);
    const uint16_t* bsrc0 = Wt + ((size_t)(p * H_ + nt * 4 + ((t >> 2) >> 6)) * A_ + ((t >> 2) & 63)) * D_ + bslot * 8;
    const uint16_t* bsrc1 = Wt + ((size_t)(p * H_ + nt * 4 + (((t >> 2) + 128) >> 6)) * A_ + ((t >> 2) & 63)) * D_ + bslot * 8;

    f32x4 acc[4][4] = {};

    #define BSTAGE(buf, kkv) do {                                                                  \
        __builtin_amdgcn_global_load_lds(bsrc0 + (kkv), (char*)(&Bs[buf][0]) + w * 1024,        16, 0, 0); \
        __builtin_amdgcn_global_load_lds(bsrc1 + (kkv), (char*)(&Bs[buf][0]) + 8192 + w * 1024, 16, 0, 0); \
    } while (0)

    #define AWRITE(buf, v0, v1) do {                                                               \
        uint4 u_;                                                                                  \
        u_.x = pkrtz((v0).x, (v0).y); u_.y = pkrtz((v0).z, (v0).w);                                \
        u_.z = pkrtz((v1).x, (v1).y); u_.w = pkrtz((v1).z, (v1).w);                                \
        *(uint4*)(&As[buf][awoff]) = u_;                                                           \
    } while (0)

    #define COMPUTE(buf) do {                                                                      \
        f16x8 af[4], bf[4];                                                                        \
        _Pragma("unroll")                                                                          \
        for (int mb = 0; mb < 4; mb++) {                                                           \
            const int r = wr * 64 + mb * 16 + lr;                                                  \
            af[mb] = *(const f16x8*)(&As[buf][r * 32 + ((lg ^ ((r >> 1) & 3)) * 8)]);              \
        }                                                                                          \
        _Pragma("unroll")                                                                          \
        for (int nb = 0; nb < 4; nb++) {                                                           \
            const int r = wc * 64 + nb * 16 + lr;                                                  \
            bf[nb] = *(const f16x8*)(&Bs[buf][r * 32 + ((lg ^ ((r >> 1) & 3)) * 8)]);              \
        }                                                                                          \
        _Pragma("unroll")                                                                          \
        for (int mb = 0; mb < 4; mb++) {                                                           \
            _Pragma("unroll")                                                                      \
            for (int nb = 0; nb < 4; nb++)                                                         \
                acc[mb][nb] = __builtin_amdgcn_mfma_f32_16x16x32_f16(af[mb], bf[nb], acc[mb][nb], 0, 0, 0); \
        }                                                                                          \
    } while (0)

    float4 e0, e1, o0, o1;
    BSTAGE(0, 0);
    __builtin_amdgcn_sched_barrier(0);
    e0 = *(const float4*)(asrc);
    e1 = *(const float4*)(asrc + 4);
    asm volatile("s_waitcnt vmcnt(0)" ::: "memory");
    AWRITE(0, e0, e1);
    __syncthreads();
    o0 = *(const float4*)(asrc + 32);
    o1 = *(const float4*)(asrc + 36);
    __builtin_amdgcn_sched_barrier(0);

    const int NKS = D_ / 32;   // 32 (even)
    for (int ks = 0; ks < NKS; ks += 2) {
        BSTAGE(1, (ks + 1) * 32);
        __builtin_amdgcn_sched_barrier(0);
        if (ks + 2 < NKS) {
            e0 = *(const float4*)(asrc + (ks + 2) * 32);
            e1 = *(const float4*)(asrc + (ks + 2) * 32 + 4);
        }
        __builtin_amdgcn_sched_barrier(0);
        COMPUTE(0);
        if (ks + 2 < NKS) asm volatile("s_waitcnt vmcnt(2)" ::: "memory");
        else              asm volatile("s_waitcnt vmcnt(0)" ::: "memory");
        __builtin_amdgcn_sched_barrier(0);
        AWRITE(1, o0, o1);
        asm volatile("s_waitcnt lgkmcnt(0)" ::: "memory");
        __builtin_amdgcn_s_barrier();
        __builtin_amdgcn_sched_barrier(0);

        if (ks + 2 < NKS) {
            BSTAGE(0, (ks + 2) * 32);
            __builtin_amdgcn_sched_barrier(0);
            if (ks + 3 < NKS) {
                o0 = *(const float4*)(asrc + (ks + 3) * 32);
                o1 = *(const float4*)(asrc + (ks + 3) * 32 + 4);
            }
            __builtin_amdgcn_sched_barrier(0);
        }
        COMPUTE(1);
        if (ks + 2 < NKS) {
            if (ks + 3 < NKS) asm volatile("s_waitcnt vmcnt(2)" ::: "memory");
            else              asm volatile("s_waitcnt vmcnt(0)" ::: "memory");
            __builtin_amdgcn_sched_barrier(0);
            AWRITE(0, e0, e1);
            asm volatile("s_waitcnt lgkmcnt(0)" ::: "memory");
            __builtin_amdgcn_s_barrier();
            __builtin_amdgcn_sched_barrier(0);
        }
    }
    #undef BSTAGE
    #undef AWRITE
    #undef COMPUTE

    const int h = nt * 4 + wc;
    const int b = Mbase >> 11;
    const int bh = b * H_ + h;
    const int sbase = Mbase & (S_ - 1);
    const float* bias = ((p == 0) ? bq : (p == 1) ? bk : bv) + h * A_;
    const float bsc = (p == 0) ? INV_LN2 : 1.0f;
    #pragma unroll
    for (int mb = 0; mb < 4; mb++) {
        #pragma unroll
        for (int nb = 0; nb < 4; nb++) {
            const int a = nb * 16 + lr;
            const float bia = bias[a] * bsc;
            const int s0 = sbase + wr * 64 + mb * 16 + 4 * lg;
            if (p < 2) {
                uint16_t* o = (p == 0) ? qh : kh;
                #pragma unroll
                for (int r = 0; r < 4; r++)
                    o[(bh * S_ + s0 + r) * A_ + a] = (uint16_t)f2h(acc[mb][nb][r] + bia);
            } else {
                const int kt2 = s0 >> 6, kv0 = s0 & 63;
                const int kb2 = kv0 >> 5, jhi = (kv0 >> 4) & 1, lg2 = (kv0 >> 2) & 3;
                uint2 pk2;
                pk2.x = f2h(acc[mb][nb][0] + bia) | (f2h(acc[mb][nb][1] + bia) << 16);
                pk2.y = f2h(acc[mb][nb][2] + bia) | (f2h(acc[mb][nb][3] + bia) << 16);
                *(uint2*)(vpv + ((size_t)((bh * 32 + kt2) * 512 + kb2 * 256 + lg2 * 64 + a)) * 8 + 4 * jhi) = pk2;
            }
        }
    }
}

// ---------------------------------------------------------------- flash attention
// QBLK=256 (two 16-row groups per wave, serial) x KVBLK=128 (two 64-kv halves
// per tile, serial) -> 72 MFMA + 4 softmax slices per wait+barrier; barrier
// count 32 -> 16. 2-deep 128-wide K/V (64 KB LDS, 2 blocks/CU, grid 512 =
// exactly 2/CU, zero tail). proj-pattern schedule: stage(t+1) issued at tile
// top (buffer freed by end-of-(t-1) barrier), compute covers the loads
// (~1300 cyc > HBM 900), vmcnt(0)+raw barrier at tile end. XCD remap, swapped
// QK^T with C-init = -m, per-lane defer-check, l-sum via ones-MFMA, pkrtz,
// full-line stores via two-pass LDS restage.
__global__ __launch_bounds__(512, 4) void flash_kernel(
    const uint16_t* __restrict__ qh, const uint16_t* __restrict__ kh,
    const uint16_t* __restrict__ vpv, float* __restrict__ out)
{
    __shared__ __align__(16) uint16_t smem[32768];   // K[2][8192]: 0..16383 | V[2][8192]: 16384..32767
    const int t = threadIdx.x, lane = t & 63, w = t >> 6;   // w: 0..7
    const int lr = lane & 15, lg = lane >> 4;

    // XCD-locality remap: 8 same-XCD bh's, each with all 8 qt tiles
    const int flat = blockIdx.x;                     // 0..511
    const int nf = (flat & 7) * 64 + (flat >> 3);
    const int qt = nf & 7, bh = nf >> 3;
    const int b = bh >> 4, h = bh & (H_ - 1);

    // Q as B-fragment, two groups: rows qt*256 + g*128 + w*16 + lr
    f16x8 qf0[2], qf1[2];
    {
        const uint16_t* qp0 = qh + (size_t)(bh * S_ + qt * 256 + w * 16 + lr) * A_ + 8 * lg;
        qf0[0] = *(const f16x8*)(qp0);
        qf0[1] = *(const f16x8*)(qp0 + 32);
        const uint16_t* qp1 = qp0 + (size_t)128 * A_;
        qf1[0] = *(const f16x8*)(qp1);
        qf1[1] = *(const f16x8*)(qp1 + 32);
    }
    f16x8 ones;
    #pragma unroll
    for (int j = 0; j < 8; j++) ones[j] = (_Float16)1.0f;

    // Staging: 512 lanes x 16 B = 8 KB per instruction; 128-row tile = 2 instrs.
    const int row0 = t >> 3;           // 0..63
    const int col0 = (t * 8) & 63;
    const int scol = col0 ^ ((row0 & 7) << 3);
    const uint16_t* kg = kh + (size_t)(bh * S_ + row0) * A_ + scol;
    const uint16_t* vg = vpv + (size_t)bh * (S_ * A_) + t * 8;

    f32x4 negm0 = {}, negm1 = {};
    f32x4 oacc0[4] = {}, oacc1[4] = {};
    f32x4 lsum0 = {}, lsum1 = {};

    #define FSTAGE(buf, kt_) do {                                                               \
        __builtin_amdgcn_global_load_lds(kg + (size_t)((kt_) * 128) * A_,                       \
                                         smem + (buf) * 8192 + w * 512, 16, 0, 0);              \
        __builtin_amdgcn_global_load_lds(kg + (size_t)((kt_) * 128 + 64) * A_,                  \
                                         smem + (buf) * 8192 + 4096 + w * 512, 16, 0, 0);       \
        __builtin_amdgcn_global_load_lds(vg + (size_t)(kt_) * 8192,                             \
                                         smem + 16384 + (buf) * 8192 + w * 512, 16, 0, 0);      \
        __builtin_amdgcn_global_load_lds(vg + (size_t)(kt_) * 8192 + 4096,                      \
                                         smem + 16384 + (buf) * 8192 + 4096 + w * 512, 16, 0, 0);\
    } while (0)

    // One group's QK -> defer-max softmax -> paf -> lsum for a 64-kv half.
    #define GBODY(QF, NEGM, OACC, LSUM, PAF, Kc) do {                                           \
        f32x4 sacc[4];                                                                          \
        __builtin_amdgcn_s_setprio(1);                                                          \
        _Pragma("unroll")                                                                       \
        for (int nb = 0; nb < 4; nb++) {                                                        \
            f16x8 kf = *(const f16x8*)((Kc) + swz(nb * 16 + lr, 8 * lg));                       \
            sacc[nb] = __builtin_amdgcn_mfma_f32_16x16x32_f16(kf, (QF)[0], NEGM, 0, 0, 0);      \
        }                                                                                       \
        _Pragma("unroll")                                                                       \
        for (int nb = 0; nb < 4; nb++) {                                                        \
            f16x8 kf = *(const f16x8*)((Kc) + swz(nb * 16 + lr, 32 + 8 * lg));                  \
            sacc[nb] = __builtin_amdgcn_mfma_f32_16x16x32_f16(kf, (QF)[1], sacc[nb], 0, 0, 0);  \
        }                                                                                       \
        __builtin_amdgcn_s_setprio(0);                                                          \
        float a0 = fmaxf(fmaxf(sacc[0][0], sacc[0][1]), sacc[0][2]);                            \
        float a1 = fmaxf(fmaxf(sacc[0][3], sacc[1][0]), sacc[1][1]);                            \
        float a2 = fmaxf(fmaxf(sacc[1][2], sacc[1][3]), sacc[2][0]);                            \
        float a3 = fmaxf(fmaxf(sacc[2][1], sacc[2][2]), sacc[2][3]);                            \
        float a4 = fmaxf(fmaxf(sacc[3][0], sacc[3][1]), sacc[3][2]);                            \
        float pm = fmaxf(fmaxf(fmaxf(a0, a1), fmaxf(a2, a3)), fmaxf(a4, sacc[3][3]));           \
        if (__any(pm > 11.0f)) {                                                                \
            float tm = fmaxf(pm, __shfl_xor(pm, 16));                                           \
            tm = fmaxf(tm, __shfl_xor(tm, 32));                                                 \
            float delta = fmaxf(tm, 0.0f);                                                      \
            float sc = exp2f_fast(-delta);                                                      \
            _Pragma("unroll")                                                                   \
            for (int r = 0; r < 4; r++) (NEGM)[r] -= delta;                                     \
            _Pragma("unroll")                                                                   \
            for (int nb = 0; nb < 4; nb++)                                                      \
                _Pragma("unroll")                                                               \
                for (int r = 0; r < 4; r++) sacc[nb][r] -= delta;                               \
            float scr[4];                                                                       \
            _Pragma("unroll")                                                                   \
            for (int r = 0; r < 4; r++) scr[r] = __shfl(sc, 4 * lg + r);                        \
            _Pragma("unroll")                                                                   \
            for (int r = 0; r < 4; r++) (LSUM)[r] *= scr[r];                                    \
            _Pragma("unroll")                                                                   \
            for (int nb = 0; nb < 4; nb++)                                                      \
                _Pragma("unroll")                                                               \
                for (int r = 0; r < 4; r++) (OACC)[nb][r] *= scr[r];                            \
        }                                                                                       \
        _Pragma("unroll")                                                                       \
        for (int kb2 = 0; kb2 < 2; kb2++) {                                                     \
            float e[8];                                                                         \
            _Pragma("unroll")                                                                   \
            for (int jh = 0; jh < 2; jh++)                                                      \
                _Pragma("unroll")                                                               \
                for (int r = 0; r < 4; r++)                                                     \
                    e[jh * 4 + r] = exp2f_fast(sacc[2 * kb2 + jh][r]);                          \
            uint4 u;                                                                            \
            u.x = pkrtz(e[0], e[1]); u.y = pkrtz(e[2], e[3]);                                   \
            u.z = pkrtz(e[4], e[5]); u.w = pkrtz(e[6], e[7]);                                   \
            (PAF)[kb2] = __builtin_bit_cast(f16x8, u);                                          \
        }                                                                                       \
        (LSUM) = __builtin_amdgcn_mfma_f32_16x16x32_f16((PAF)[0], ones, LSUM, 0, 0, 0);         \
        (LSUM) = __builtin_amdgcn_mfma_f32_16x16x32_f16((PAF)[1], ones, LSUM, 0, 0, 0);         \
    } while (0)

    const int NT = S_ / 128;   // 16
    FSTAGE(0, 0);
    asm volatile("s_waitcnt vmcnt(0)" ::: "memory");
    __builtin_amdgcn_s_barrier();
    __builtin_amdgcn_sched_barrier(0);

    for (int kt = 0; kt < NT; kt++) {
        const int cur = kt & 1;
        if (kt + 1 < NT) FSTAGE(cur ^ 1, kt + 1);   // buf^1 freed by end-of-(kt-1) barrier
        __builtin_amdgcn_sched_barrier(0);

        #pragma unroll
        for (int half = 0; half < 2; half++) {
            const uint16_t* Kc = smem + cur * 8192 + half * 4096;
            const uint16_t* Vc = smem + 16384 + cur * 8192 + half * 4096;
            f16x8 paf0[2], paf1[2];
            GBODY(qf0, negm0, oacc0, lsum0, paf0, Kc);
            GBODY(qf1, negm1, oacc1, lsum1, paf1, Kc);
            __builtin_amdgcn_s_setprio(1);
            #pragma unroll
            for (int kb2 = 0; kb2 < 2; kb2++) {
                #pragma unroll
                for (int nb = 0; nb < 4; nb++) {
                    f16x8 vf = *(const f16x8*)(Vc + ((kb2 * 4 + lg) * 64 + nb * 16 + lr) * 8);
                    oacc0[nb] = __builtin_amdgcn_mfma_f32_16x16x32_f16(paf0[kb2], vf, oacc0[nb], 0, 0, 0);
                    oacc1[nb] = __builtin_amdgcn_mfma_f32_16x16x32_f16(paf1[kb2], vf, oacc1[nb], 0, 0, 0);
                }
            }
            __builtin_amdgcn_s_setprio(0);
        }

        if (kt + 1 < NT) {
            asm volatile("s_waitcnt vmcnt(0)" ::: "memory");   // stage(kt+1) landed (covered by this tile's compute)
            __builtin_amdgcn_s_barrier();                      // all waves done with buf cur + next tile data visible
            __builtin_amdgcn_sched_barrier(0);
        }
    }
    #undef FSTAGE
    #undef GBODY

    // normalize + store, two passes through 32 KB LDS restage
    float* outs = (float*)smem;   // 128 x 64 f32 = 32 KB
    const int orow = t >> 4, oslot = t & 15;
    #pragma unroll
    for (int g = 0; g < 2; g++) {
        __syncthreads();   // all waves done with K/V LDS (g=0) / prev restage (g=1)
        #pragma unroll
        for (int r = 0; r < 4; r++) {
            const int sl = w * 16 + 4 * lg + r;
            if (g == 0) {
                const float inv = 1.0f / lsum0[r];
                #pragma unroll
                for (int nb = 0; nb < 4; nb++)
                    outs[sl * 64 + nb * 16 + lr] = oacc0[nb][r] * inv;
            } else {
                const float inv = 1.0f / lsum1[r];
                #pragma unroll
                for (int nb = 0; nb < 4; nb++)
                    outs[sl * 64 + nb * 16 + lr] = oacc1[nb][r] * inv;
            }
        }
        __syncthreads();
        float* obase = out + (size_t)(b * S_ + qt * 256 + g * 128 + orow) * (H_ * A_) + h * A_ + oslot * 4;
        #pragma unroll
        for (int i = 0; i < 4; i++)
            *(float4*)(obase + (size_t)(32 * i) * (H_ * A_)) =
                *(const float4*)(outs + (orow + 32 * i) * 64 + oslot * 4);
    }
}

// ----------------------------------------------------------------
extern "C" void kernel_launch(void* const* d_in, const int* in_sizes, int n_in,
                              void* d_out, int out_size, void* d_ws, size_t ws_size,
                              hipStream_t stream)
{
    const float* q  = (const float*)d_in[0];
    const float* k  = (const float*)d_in[1];
    const float* v  = (const float*)d_in[2];
    const float* Wq = (const float*)d_in[3];
    const float* bq = (const float*)d_in[4];
    const float* Wk = (const float*)d_in[5];
    const float* bk = (const float*)d_in[6];
    const float* Wv = (const float*)d_in[7];
    const float* bv = (const float*)d_in[8];
    float* out = (float*)d_out;

    uint8_t* ws = (uint8_t*)d_ws;
    const size_t SZ_H  = (size_t)BH_ * S_ * A_ * 2;     // 16 MB each
    uint16_t* qh  = (uint16_t*)(ws);
    uint16_t* kh  = (uint16_t*)(ws + SZ_H);
    uint16_t* vpv = (uint16_t*)(ws + 2 * SZ_H);
    uint16_t* Wt  = (uint16_t*)(ws + 3 * SZ_H);

    prep_w<<<dim3(16, H_, 3), 256, 0, stream>>>(Wq, Wk, Wv, Wt);
    proj_kernel<<<dim3(M_ / 128, 4, 3), 512, 0, stream>>>(q, k, v, Wt,
                                                          bq, bk, bv, qh, kh, vpv);
    flash_kernel<<<dim3(S_ / 256 * BH_), 512, 0, stream>>>(qh, kh, vpv, out);
}